// Round 2
// baseline (870.525 us; speedup 1.0000x reference)
//
#include <hip/hip_runtime.h>
#include <cfloat>
#include <cmath>

// ---------------- workspace layout (floats) ----------------
#define WS_XR     0        // 16*512 = 8192   x_r = fast_attention(inputs, fa_r)
#define WS_UPDW   8192     // 48              sigmoid gate upd_w[b][i]
#define WS_READW  8240     // 48              tanh(max) read_w[b][i]
#define WS_PMAX   8288     // 3*16*79 = 3792  per-tile max partials
#define WS_PIDX   12080    // 3792 (ints)     per-tile argmax partials
#define WS_RNEW   15872    // 48*256 = 12288  gated r' rows
#define WS_SINK   28160    // 1024            prefetch DCE sink
// total 29184 floats = 114 KB

constexpr int NTILES = 79;   // ceil(10000 / 128)

// ---------------- reductions (wave = 64) ----------------
__device__ __forceinline__ float wave_sum(float v) {
#pragma unroll
  for (int o = 32; o > 0; o >>= 1) v += __shfl_xor(v, o);
  return v;
}
__device__ __forceinline__ float wave_max(float v) {
#pragma unroll
  for (int o = 32; o > 0; o >>= 1) v = fmaxf(v, __shfl_xor(v, o));
  return v;
}
__device__ __forceinline__ float block_sum(float v, float* red) {
  int lane = threadIdx.x & 63, w = threadIdx.x >> 6, nw = blockDim.x >> 6;
  v = wave_sum(v);
  __syncthreads();                 // protect red from previous use
  if (lane == 0) red[w] = v;
  __syncthreads();
  float s = 0.f;
  for (int k = 0; k < nw; k++) s += red[k];
  return s;
}
__device__ __forceinline__ float block_max(float v, float* red) {
  int lane = threadIdx.x & 63, w = threadIdx.x >> 6, nw = blockDim.x >> 6;
  v = wave_max(v);
  __syncthreads();
  if (lane == 0) red[w] = v;
  __syncthreads();
  float s = -FLT_MAX;
  for (int k = 0; k < nw; k++) s = fmaxf(s, red[k]);
  return s;
}

// ---------------- K0: prefetch all small weight matrices into L2/L3 ----------------
// The harness's 238 MB d_in restore before each replay evicts L3; every
// downstream kernel is latency-bound on cold weights. 256 blocks stream the
// 12.3 MB of small weights BW-bound (~2 us) so later reads are L2/L3 hits.
__global__ __launch_bounds__(256) void k_prefetch(
    const float* __restrict__ w1r, const float* __restrict__ w2r,
    const float* __restrict__ w1u, const float* __restrict__ w2u,
    const float* __restrict__ w1um, const float* __restrict__ w2um,
    const float* __restrict__ Wum,
    const float* __restrict__ w1am, const float* __restrict__ w2am,
    const float* __restrict__ Wam, float* __restrict__ sink) {
  int tid = threadIdx.x;
  int g = blockIdx.x * 256 + tid;
  const int STR = 256 * 256;
  float s = 0.f;
#define PF(p, n4)                                         \
  for (int i = g; i < (n4); i += STR) {                   \
    float4 v = ((const float4*)(p))[i];                   \
    s += v.x + v.y + v.z + v.w;                           \
  }
  PF(w1r, 65536)  PF(w2r, 65536)   // 512x512
  PF(w1u, 65536)  PF(w2u, 65536)
  PF(w1um, 147456) PF(w2um, 147456) // 768x768
  PF(Wum, 49152)                    // 768x256
  PF(w1am, 65536) PF(w2am, 65536)  // 512x512
  PF(Wam, 32768)                    // 512x256
#undef PF
  s = wave_sum(s);
  if ((tid & 63) == 0) sink[blockIdx.x * 4 + (tid >> 6)] = s;
}

// ---------------- K1: fa_r + fa_u + upd_w (block per batch row) ----------------
__global__ __launch_bounds__(512) void k_fa_in(
    const float* __restrict__ x,
    const float* __restrict__ w1r, const float* __restrict__ b1r,
    const float* __restrict__ w2r, const float* __restrict__ b2r,
    const float* __restrict__ w1u, const float* __restrict__ b1u,
    const float* __restrict__ w2u, const float* __restrict__ b2u,
    const float* __restrict__ Wuw, const float* __restrict__ buw,
    float* __restrict__ xr_out, float* __restrict__ updw_out) {
  __shared__ float xs[512], hs[512], red[16];
  int b = blockIdx.x, tid = threadIdx.x;
  xs[tid] = x[b * 512 + tid];
  __syncthreads();

  // ---- r path: x_r = x * (softmax(x@w1r+b1r) @ w2r + b2r)
  float t = b1r[tid];
#pragma unroll 32
  for (int c = 0; c < 512; c++) t = fmaf(xs[c], w1r[c * 512 + tid], t);
  float mx = block_max(t, red);
  float e = expf(t - mx);
  float s = block_sum(e, red);
  hs[tid] = e / s;
  __syncthreads();
  float y = b2r[tid];
#pragma unroll 32
  for (int c = 0; c < 512; c++) y = fmaf(hs[c], w2r[c * 512 + tid], y);
  xr_out[b * 512 + tid] = xs[tid] * y;

  // ---- u path (block_max's internal barrier makes hs overwrite safe)
  t = b1u[tid];
#pragma unroll 32
  for (int c = 0; c < 512; c++) t = fmaf(xs[c], w1u[c * 512 + tid], t);
  mx = block_max(t, red);
  e = expf(t - mx);
  s = block_sum(e, red);
  hs[tid] = e / s;
  __syncthreads();
  y = b2u[tid];
#pragma unroll 32
  for (int c = 0; c < 512; c++) y = fmaf(hs[c], w2u[c * 512 + tid], y);
  float xu = xs[tid] * y;

  // ---- upd_w[b][i] = sigmoid(dot(x_u, W_uw[:,i]) + b_uw[i])
  for (int i = 0; i < 3; i++) {
    float p = xu * Wuw[tid * 3 + i];
    float si = block_sum(p, red);
    if (tid == 0) updw_out[b * 3 + i] = 1.f / (1.f + expf(-(si + buw[i])));
  }
}

// ---------------- K2: read matmul + per-tile max/argmax partials ----------------
// grid (79, 3); block 512 = 8 waves; wave w handles batches 2w, 2w+1;
// lane owns 2 consecutive s-columns. tanh is monotonic -> argmax on pre-activation.
__global__ __launch_bounds__(512) void k_read(
    const float* __restrict__ W, const float* __restrict__ brd,
    const float* __restrict__ xr,
    float* __restrict__ pmax, int* __restrict__ pidx) {
  __shared__ __align__(16) float xs[16 * 512];
  int tid = threadIdx.x, lane = tid & 63, w = tid >> 6;
  int i = blockIdx.y, tile = blockIdx.x;
  {
    const float4* s4 = (const float4*)xr;
    float4* d4 = (float4*)xs;
    for (int t = tid; t < 2048; t += 512) d4[t] = s4[t];
  }
  __syncthreads();
  int b0 = w * 2, b1 = b0 + 1;
  int s0 = tile * 128 + lane * 2;
  int sC = (s0 > 9998) ? 9998 : s0;            // clamp tail, mask later
  const float* Wp = W + i * 10000 + sC;
  const float* xap = xs + b0 * 512;
  const float* xbp = xs + b1 * 512;
  float a00 = 0.f, a01 = 0.f, a10 = 0.f, a11 = 0.f;
#pragma unroll 4
  for (int c = 0; c < 512; c += 4) {
    float4 xa = *(const float4*)(xap + c);
    float4 xb = *(const float4*)(xbp + c);
    float2 w0 = *(const float2*)(Wp + (size_t)(c + 0) * 30000);
    float2 w1 = *(const float2*)(Wp + (size_t)(c + 1) * 30000);
    float2 w2 = *(const float2*)(Wp + (size_t)(c + 2) * 30000);
    float2 w3 = *(const float2*)(Wp + (size_t)(c + 3) * 30000);
    a00 = fmaf(xa.x, w0.x, a00); a01 = fmaf(xa.x, w0.y, a01);
    a10 = fmaf(xb.x, w0.x, a10); a11 = fmaf(xb.x, w0.y, a11);
    a00 = fmaf(xa.y, w1.x, a00); a01 = fmaf(xa.y, w1.y, a01);
    a10 = fmaf(xb.y, w1.x, a10); a11 = fmaf(xb.y, w1.y, a11);
    a00 = fmaf(xa.z, w2.x, a00); a01 = fmaf(xa.z, w2.y, a01);
    a10 = fmaf(xb.z, w2.x, a10); a11 = fmaf(xb.z, w2.y, a11);
    a00 = fmaf(xa.w, w3.x, a00); a01 = fmaf(xa.w, w3.y, a01);
    a10 = fmaf(xb.w, w3.x, a10); a11 = fmaf(xb.w, w3.y, a11);
  }
  float2 bb = *(const float2*)(brd + i * 10000 + sC);
  bool ok0 = (s0 < 10000), ok1 = (s0 + 1 < 10000);
  float v00 = a00 + bb.x, v01 = a01 + bb.y;
  float v10 = a10 + bb.x, v11 = a11 + bb.y;
  float bv0 = ok0 ? v00 : -FLT_MAX; int bi0 = s0;
  if (ok1 && v01 > bv0) { bv0 = v01; bi0 = s0 + 1; }
  float bv1 = ok0 ? v10 : -FLT_MAX; int bi1 = s0;
  if (ok1 && v11 > bv1) { bv1 = v11; bi1 = s0 + 1; }
  // wave argmax reduce; partner lane always has strictly higher s, so
  // strict '>' keeps the lower index on ties (numpy first-max semantics).
#pragma unroll
  for (int o = 32; o > 0; o >>= 1) {
    float ov = __shfl_down(bv0, o); int oi = __shfl_down(bi0, o);
    if (ov > bv0) { bv0 = ov; bi0 = oi; }
    ov = __shfl_down(bv1, o); oi = __shfl_down(bi1, o);
    if (ov > bv1) { bv1 = ov; bi1 = oi; }
  }
  if (lane == 0) {
    int base = (i * 16 + b0) * NTILES + tile;
    pmax[base] = bv0; pidx[base] = bi0;
    base = (i * 16 + b1) * NTILES + tile;
    pmax[base] = bv1; pidx[base] = bi1;
  }
}

// ---------------- K3: argmax finalize + gather + fa_um + W_um + gate ----------------
// block per (b,i) row — all 48 update rows are independent of m.
__global__ __launch_bounds__(768) void k_um(
    const float* __restrict__ mem, const float* __restrict__ x,
    const float* __restrict__ w1, const float* __restrict__ b1,
    const float* __restrict__ w2, const float* __restrict__ b2,
    const float* __restrict__ Wum, const float* __restrict__ bum,
    const float* __restrict__ pmax, const int* __restrict__ pidx,
    const float* __restrict__ updw, float* __restrict__ readw,
    float* __restrict__ rnew) {
  __shared__ float xcs[768], hs[768], xus[768], part[768], red[16];
  __shared__ int sidx;
  int bi = blockIdx.x;
  int b = bi / 3, i = bi % 3;
  int tid = threadIdx.x, lane = tid & 63, w = tid >> 6;

  // 1. reduce the 79 tile partials -> read_idx, read_w
  if (w == 0) {
    float bv = -FLT_MAX; int bix = 0;
    const float* pm = pmax + (i * 16 + b) * NTILES;
    const int* pi = pidx + (i * 16 + b) * NTILES;
    for (int t = lane; t < NTILES; t += 64) {
      float v = pm[t]; int ix = pi[t];
      if (v > bv || (v == bv && ix < bix)) { bv = v; bix = ix; }
    }
#pragma unroll
    for (int o = 32; o > 0; o >>= 1) {
      float ov = __shfl_down(bv, o); int oi = __shfl_down(bix, o);
      if (ov > bv || (ov == bv && oi < bix)) { bv = ov; bix = oi; }
    }
    if (lane == 0) { sidx = bix; readw[b * 3 + i] = tanhf(bv); }
  }
  __syncthreads();

  // 2. xc = concat(memory[b, idx], inputs[b])
  if (tid < 256) xcs[tid] = mem[((size_t)b * 10000 + sidx) * 256 + tid];
  else           xcs[tid] = x[b * 512 + (tid - 256)];
  __syncthreads();

  // 3. t = xc@w1 + b1 ; softmax
  float t = b1[tid];
#pragma unroll 32
  for (int c = 0; c < 768; c++) t = fmaf(xcs[c], w1[c * 768 + tid], t);
  float mx = block_max(t, red);
  float e = expf(t - mx);
  float s = block_sum(e, red);
  hs[tid] = e / s;
  __syncthreads();

  // 4. xu = xc * (h@w2 + b2)
  float y = b2[tid];
#pragma unroll 32
  for (int c = 0; c < 768; c++) y = fmaf(hs[c], w2[c * 768 + tid], y);
  xus[tid] = xcs[tid] * y;
  __syncthreads();

  // 5. upd = relu(xu@W_um + b_um); r' = u*upd + (1-u)*r   (3-way split-K)
  int jj = tid & 255, ph = tid >> 8;   // ph in 0..2
  float p = 0.f;
  int c0 = ph * 256;
#pragma unroll 32
  for (int cc = 0; cc < 256; cc++) { int c = c0 + cc; p = fmaf(xus[c], Wum[c * 256 + jj], p); }
  part[tid] = p;
  __syncthreads();
  if (tid < 256) {
    float sum = part[tid] + part[tid + 256] + part[tid + 512] + bum[tid];
    float upd = fmaxf(sum, 0.f);
    float u = updw[b * 3 + i];
    rnew[(b * 3 + i) * 256 + tid] = u * upd + (1.f - u) * xcs[tid];
  }
}

// ---------------- K4: sequential fa_am chain (3 iters) + tanh -> out ----------------
// block per batch row; m carried in LDS across iterations.
__global__ __launch_bounds__(512) void k_am(
    const float* __restrict__ w1, const float* __restrict__ b1,
    const float* __restrict__ w2, const float* __restrict__ b2,
    const float* __restrict__ Wam, const float* __restrict__ bam,
    const float* __restrict__ rnew, const float* __restrict__ readw,
    float* __restrict__ out) {
  __shared__ float xc[512], hs[512], xa[512], part[512], ms[256], red[16];
  int b = blockIdx.x, tid = threadIdx.x;
  if (tid < 256) ms[tid] = 0.f;
  __syncthreads();
  for (int i = 0; i < 3; i++) {
    if (tid < 256) xc[tid] = rnew[(b * 3 + i) * 256 + tid];
    else           xc[tid] = ms[tid - 256];
    __syncthreads();
    float t = b1[tid];
#pragma unroll 32
    for (int c = 0; c < 512; c++) t = fmaf(xc[c], w1[c * 512 + tid], t);
    float mx = block_max(t, red);
    float e = expf(t - mx);
    float s = block_sum(e, red);
    hs[tid] = e / s;
    __syncthreads();
    float y = b2[tid];
#pragma unroll 32
    for (int c = 0; c < 512; c++) y = fmaf(hs[c], w2[c * 512 + tid], y);
    xa[tid] = xc[tid] * y;
    __syncthreads();
    int jj = tid & 255, ph = tid >> 8;   // 2-way split-K
    float p = 0.f;
    int c0 = ph * 256;
#pragma unroll 32
    for (int cc = 0; cc < 256; cc++) { int c = c0 + cc; p = fmaf(xa[c], Wam[c * 256 + jj], p); }
    part[tid] = p;
    __syncthreads();
    if (tid < 256) {
      float sum = part[tid] + part[tid + 256] + bam[tid];
      ms[tid] = readw[b * 3 + i] * fmaxf(sum, 0.f);
    }
    __syncthreads();
  }
  if (tid < 256) out[b * 256 + tid] = tanhf(ms[tid]);
}

// ---------------- launch ----------------
extern "C" void kernel_launch(void* const* d_in, const int* in_sizes, int n_in,
                              void* d_out, int out_size, void* d_ws, size_t ws_size,
                              hipStream_t stream) {
  const float* x    = (const float*)d_in[0];
  const float* mem  = (const float*)d_in[1];
  const float* w1r  = (const float*)d_in[2];
  const float* b1r  = (const float*)d_in[3];
  const float* w2r  = (const float*)d_in[4];
  const float* b2r  = (const float*)d_in[5];
  const float* Wrd  = (const float*)d_in[6];
  const float* brd  = (const float*)d_in[7];
  const float* w1u  = (const float*)d_in[8];
  const float* b1u  = (const float*)d_in[9];
  const float* w2u  = (const float*)d_in[10];
  const float* b2u  = (const float*)d_in[11];
  const float* Wuw  = (const float*)d_in[12];
  const float* buw  = (const float*)d_in[13];
  const float* w1um = (const float*)d_in[14];
  const float* b1um = (const float*)d_in[15];
  const float* w2um = (const float*)d_in[16];
  const float* b2um = (const float*)d_in[17];
  const float* Wum  = (const float*)d_in[18];
  const float* bum  = (const float*)d_in[19];
  const float* w1am = (const float*)d_in[20];
  const float* b1am = (const float*)d_in[21];
  const float* w2am = (const float*)d_in[22];
  const float* b2am = (const float*)d_in[23];
  const float* Wam  = (const float*)d_in[24];
  const float* bam  = (const float*)d_in[25];

  float* ws   = (float*)d_ws;
  float* xr   = ws + WS_XR;
  float* updw = ws + WS_UPDW;
  float* rdw  = ws + WS_READW;
  float* pmax = ws + WS_PMAX;
  int*   pidx = (int*)(ws + WS_PIDX);
  float* rnew = ws + WS_RNEW;
  float* sink = ws + WS_SINK;
  float* out  = (float*)d_out;

  k_prefetch<<<256, 256, 0, stream>>>(w1r, w2r, w1u, w2u, w1um, w2um, Wum,
                                      w1am, w2am, Wam, sink);
  k_fa_in<<<16, 512, 0, stream>>>(x, w1r, b1r, w2r, b2r, w1u, b1u, w2u, b2u,
                                  Wuw, buw, xr, updw);
  k_read<<<dim3(NTILES, 3), 512, 0, stream>>>(Wrd, brd, xr, pmax, pidx);
  k_um<<<48, 768, 0, stream>>>(mem, x, w1um, b1um, w2um, b2um, Wum, bum,
                               pmax, pidx, updw, rdw, rnew);
  k_am<<<16, 512, 0, stream>>>(w1am, b1am, w2am, b2am, Wam, bam, rnew, rdw, out);
}

// Round 3
// 521.556 us; speedup vs baseline: 1.6691x; 1.6691x over previous
//
#include <hip/hip_runtime.h>
#include <cfloat>
#include <cmath>

// ---------------- workspace layout (floats) ----------------
#define WS_XR     0        // 16*512 = 8192   x_r = fast_attention(inputs, fa_r)
#define WS_UPDW   8192     // 48              sigmoid gate upd_w[b][i]
#define WS_READW  8240     // 48              tanh(max) read_w[b][i]
#define WS_PMAX   8288     // 3*16*79 = 3792  per-tile max partials
#define WS_PIDX   12080    // 3792 (ints)     per-tile argmax partials
#define WS_RNEW   15872    // 48*256 = 12288  gated r' rows
// total 28160 floats = 110 KB

constexpr int NTILES = 79;   // ceil(10000 / 128)

// ---------------- reductions (wave = 64) ----------------
__device__ __forceinline__ float wave_sum(float v) {
#pragma unroll
  for (int o = 32; o > 0; o >>= 1) v += __shfl_xor(v, o);
  return v;
}
__device__ __forceinline__ float wave_max(float v) {
#pragma unroll
  for (int o = 32; o > 0; o >>= 1) v = fmaxf(v, __shfl_xor(v, o));
  return v;
}
__device__ __forceinline__ float block_sum(float v, float* red) {
  int lane = threadIdx.x & 63, w = threadIdx.x >> 6, nw = blockDim.x >> 6;
  v = wave_sum(v);
  __syncthreads();                 // protect red from previous use
  if (lane == 0) red[w] = v;
  __syncthreads();
  float s = 0.f;
  for (int k = 0; k < nw; k++) s += red[k];
  return s;
}
__device__ __forceinline__ float block_max(float v, float* red) {
  int lane = threadIdx.x & 63, w = threadIdx.x >> 6, nw = blockDim.x >> 6;
  v = wave_max(v);
  __syncthreads();
  if (lane == 0) red[w] = v;
  __syncthreads();
  float s = -FLT_MAX;
  for (int k = 0; k < nw; k++) s = fmaxf(s, red[k]);
  return s;
}

// Quad-column matmul pass: 512 threads, W is [512 x 512] row-major.
// thread -> (jq = tid&127 owning cols 4jq..4jq+3, ks = tid>>7 owning 128 K).
// float4 weight loads (1 KB/wave/instr, coalesced); 4-way split-K partials
// in LDS. Stall groups per pass: 16 (vs 64 scalar). Returns t for j = tid.
__device__ __forceinline__ float mm512_quad(
    const float* __restrict__ xv, const float* __restrict__ W,
    float* __restrict__ part, int tid) {
  int jq = tid & 127, ks = tid >> 7;
  const float* Wp = W + jq * 4;
  int c0 = ks * 128;
  float4 acc = {0.f, 0.f, 0.f, 0.f};
#pragma unroll 8
  for (int cc = 0; cc < 128; cc++) {
    int c = c0 + cc;
    float xs = xv[c];
    float4 w = *(const float4*)(Wp + (size_t)c * 512);
    acc.x = fmaf(xs, w.x, acc.x);
    acc.y = fmaf(xs, w.y, acc.y);
    acc.z = fmaf(xs, w.z, acc.z);
    acc.w = fmaf(xs, w.w, acc.w);
  }
  ((float4*)part)[ks * 128 + jq] = acc;
  __syncthreads();
  return part[tid] + part[512 + tid] + part[1024 + tid] + part[1536 + tid];
}

// Same for 768x768 (k_um): jq = tid%192, ks = tid/192.
__device__ __forceinline__ float mm768_quad(
    const float* __restrict__ xv, const float* __restrict__ W,
    float* __restrict__ part, int tid) {
  int jq = tid % 192, ks = tid / 192;
  const float* Wp = W + jq * 4;
  int c0 = ks * 192;
  float4 acc = {0.f, 0.f, 0.f, 0.f};
#pragma unroll 8
  for (int cc = 0; cc < 192; cc++) {
    int c = c0 + cc;
    float xs = xv[c];
    float4 w = *(const float4*)(Wp + (size_t)c * 768);
    acc.x = fmaf(xs, w.x, acc.x);
    acc.y = fmaf(xs, w.y, acc.y);
    acc.z = fmaf(xs, w.z, acc.z);
    acc.w = fmaf(xs, w.w, acc.w);
  }
  ((float4*)part)[ks * 192 + jq] = acc;
  __syncthreads();
  return part[tid] + part[768 + tid] + part[1536 + tid] + part[2304 + tid];
}

// ---------------- K1: fa_r + fa_u + upd_w (block per batch row) ----------------
__global__ __launch_bounds__(512) void k_fa_in(
    const float* __restrict__ x,
    const float* __restrict__ w1r, const float* __restrict__ b1r,
    const float* __restrict__ w2r, const float* __restrict__ b2r,
    const float* __restrict__ w1u, const float* __restrict__ b1u,
    const float* __restrict__ w2u, const float* __restrict__ b2u,
    const float* __restrict__ Wuw, const float* __restrict__ buw,
    float* __restrict__ xr_out, float* __restrict__ updw_out) {
  __shared__ float xs[512], hs[512], part[2048], red[16];
  int b = blockIdx.x, tid = threadIdx.x;
  xs[tid] = x[b * 512 + tid];
  __syncthreads();

  // ---- r path: x_r = x * (softmax(x@w1r+b1r) @ w2r + b2r)
  float t = b1r[tid] + mm512_quad(xs, w1r, part, tid);
  float mx = block_max(t, red);
  float e = expf(t - mx);
  float s = block_sum(e, red);
  hs[tid] = e / s;
  __syncthreads();
  float y = b2r[tid] + mm512_quad(hs, w2r, part, tid);
  xr_out[b * 512 + tid] = xs[tid] * y;
  __syncthreads();               // part reads done before u-path overwrites

  // ---- u path
  t = b1u[tid] + mm512_quad(xs, w1u, part, tid);
  mx = block_max(t, red);
  e = expf(t - mx);
  s = block_sum(e, red);
  hs[tid] = e / s;
  __syncthreads();
  y = b2u[tid] + mm512_quad(hs, w2u, part, tid);
  float xu = xs[tid] * y;

  // ---- upd_w[b][i] = sigmoid(dot(x_u, W_uw[:,i]) + b_uw[i])
  for (int i = 0; i < 3; i++) {
    float p = xu * Wuw[tid * 3 + i];
    float si = block_sum(p, red);
    if (tid == 0) updw_out[b * 3 + i] = 1.f / (1.f + expf(-(si + buw[i])));
  }
}

// ---------------- K2: read matmul + per-tile max/argmax partials ----------------
// grid (79, 3); block 512 = 8 waves; wave w handles batches 2w, 2w+1;
// lane owns 2 consecutive s-columns. tanh is monotonic -> argmax on pre-activation.
__global__ __launch_bounds__(512) void k_read(
    const float* __restrict__ W, const float* __restrict__ brd,
    const float* __restrict__ xr,
    float* __restrict__ pmax, int* __restrict__ pidx) {
  __shared__ __align__(16) float xs[16 * 512];
  int tid = threadIdx.x, lane = tid & 63, w = tid >> 6;
  int i = blockIdx.y, tile = blockIdx.x;
  {
    const float4* s4 = (const float4*)xr;
    float4* d4 = (float4*)xs;
    for (int t = tid; t < 2048; t += 512) d4[t] = s4[t];
  }
  __syncthreads();
  int b0 = w * 2, b1 = b0 + 1;
  int s0 = tile * 128 + lane * 2;
  int sC = (s0 > 9998) ? 9998 : s0;            // clamp tail, mask later
  const float* Wp = W + i * 10000 + sC;
  const float* xap = xs + b0 * 512;
  const float* xbp = xs + b1 * 512;
  float a00 = 0.f, a01 = 0.f, a10 = 0.f, a11 = 0.f;
#pragma unroll 4
  for (int c = 0; c < 512; c += 4) {
    float4 xa = *(const float4*)(xap + c);
    float4 xb = *(const float4*)(xbp + c);
    float2 w0 = *(const float2*)(Wp + (size_t)(c + 0) * 30000);
    float2 w1 = *(const float2*)(Wp + (size_t)(c + 1) * 30000);
    float2 w2 = *(const float2*)(Wp + (size_t)(c + 2) * 30000);
    float2 w3 = *(const float2*)(Wp + (size_t)(c + 3) * 30000);
    a00 = fmaf(xa.x, w0.x, a00); a01 = fmaf(xa.x, w0.y, a01);
    a10 = fmaf(xb.x, w0.x, a10); a11 = fmaf(xb.x, w0.y, a11);
    a00 = fmaf(xa.y, w1.x, a00); a01 = fmaf(xa.y, w1.y, a01);
    a10 = fmaf(xb.y, w1.x, a10); a11 = fmaf(xb.y, w1.y, a11);
    a00 = fmaf(xa.z, w2.x, a00); a01 = fmaf(xa.z, w2.y, a01);
    a10 = fmaf(xb.z, w2.x, a10); a11 = fmaf(xb.z, w2.y, a11);
    a00 = fmaf(xa.w, w3.x, a00); a01 = fmaf(xa.w, w3.y, a01);
    a10 = fmaf(xb.w, w3.x, a10); a11 = fmaf(xb.w, w3.y, a11);
  }
  float2 bb = *(const float2*)(brd + i * 10000 + sC);
  bool ok0 = (s0 < 10000), ok1 = (s0 + 1 < 10000);
  float v00 = a00 + bb.x, v01 = a01 + bb.y;
  float v10 = a10 + bb.x, v11 = a11 + bb.y;
  float bv0 = ok0 ? v00 : -FLT_MAX; int bi0 = s0;
  if (ok1 && v01 > bv0) { bv0 = v01; bi0 = s0 + 1; }
  float bv1 = ok0 ? v10 : -FLT_MAX; int bi1 = s0;
  if (ok1 && v11 > bv1) { bv1 = v11; bi1 = s0 + 1; }
  // wave argmax reduce; partner lane always has strictly higher s, so
  // strict '>' keeps the lower index on ties (numpy first-max semantics).
#pragma unroll
  for (int o = 32; o > 0; o >>= 1) {
    float ov = __shfl_down(bv0, o); int oi = __shfl_down(bi0, o);
    if (ov > bv0) { bv0 = ov; bi0 = oi; }
    ov = __shfl_down(bv1, o); oi = __shfl_down(bi1, o);
    if (ov > bv1) { bv1 = ov; bi1 = oi; }
  }
  if (lane == 0) {
    int base = (i * 16 + b0) * NTILES + tile;
    pmax[base] = bv0; pidx[base] = bi0;
    base = (i * 16 + b1) * NTILES + tile;
    pmax[base] = bv1; pidx[base] = bi1;
  }
}

// ---------------- K3: argmax finalize + gather + fa_um + W_um + gate ----------------
// block per (b,i) row — all 48 update rows are independent of m.
__global__ __launch_bounds__(768) void k_um(
    const float* __restrict__ mem, const float* __restrict__ x,
    const float* __restrict__ w1, const float* __restrict__ b1,
    const float* __restrict__ w2, const float* __restrict__ b2,
    const float* __restrict__ Wum, const float* __restrict__ bum,
    const float* __restrict__ pmax, const int* __restrict__ pidx,
    const float* __restrict__ updw, float* __restrict__ readw,
    float* __restrict__ rnew) {
  __shared__ float xcs[768], hs[768], part[3072], red[16];
  __shared__ int sidx;
  int bi = blockIdx.x;
  int b = bi / 3, i = bi % 3;
  int tid = threadIdx.x, lane = tid & 63, w = tid >> 6;

  // 1. reduce the 79 tile partials -> read_idx, read_w
  if (w == 0) {
    float bv = -FLT_MAX; int bix = 0;
    const float* pm = pmax + (i * 16 + b) * NTILES;
    const int* pi = pidx + (i * 16 + b) * NTILES;
    for (int t = lane; t < NTILES; t += 64) {
      float v = pm[t]; int ix = pi[t];
      if (v > bv || (v == bv && ix < bix)) { bv = v; bix = ix; }
    }
#pragma unroll
    for (int o = 32; o > 0; o >>= 1) {
      float ov = __shfl_down(bv, o); int oi = __shfl_down(bix, o);
      if (ov > bv || (ov == bv && oi < bix)) { bv = ov; bix = oi; }
    }
    if (lane == 0) { sidx = bix; readw[b * 3 + i] = tanhf(bv); }
  }
  __syncthreads();

  // 2. xc = concat(memory[b, idx], inputs[b])
  if (tid < 256) xcs[tid] = mem[((size_t)b * 10000 + sidx) * 256 + tid];
  else           xcs[tid] = x[b * 512 + (tid - 256)];
  __syncthreads();

  // 3. t = xc@w1 + b1 ; softmax
  float t = b1[tid] + mm768_quad(xcs, w1, part, tid);
  float mx = block_max(t, red);
  float e = expf(t - mx);
  float s = block_sum(e, red);
  hs[tid] = e / s;
  __syncthreads();

  // 4. xu = xc * (h@w2 + b2)
  float y = b2[tid] + mm768_quad(hs, w2, part, tid);
  float xuv = xcs[tid] * y;
  __syncthreads();               // part reads done before step-5 overwrite
  hs[tid] = xuv;                 // reuse hs as xu buffer
  __syncthreads();

  // 5. upd = relu(xu@W_um + b_um); r' = u*upd + (1-u)*r
  // quad-col 12-way split-K: jq owns cols 4jq..4jq+3 (256 cols), ks = tid>>6.
  {
    int jq = tid & 63, ks = tid >> 6;          // ks in 0..11
    const float* Wp = Wum + jq * 4;
    int c0 = ks * 64;
    float4 acc = {0.f, 0.f, 0.f, 0.f};
#pragma unroll 8
    for (int cc = 0; cc < 64; cc++) {
      int c = c0 + cc;
      float xv = hs[c];
      float4 wv = *(const float4*)(Wp + (size_t)c * 256);
      acc.x = fmaf(xv, wv.x, acc.x);
      acc.y = fmaf(xv, wv.y, acc.y);
      acc.z = fmaf(xv, wv.z, acc.z);
      acc.w = fmaf(xv, wv.w, acc.w);
    }
    ((float4*)part)[ks * 64 + jq] = acc;
  }
  __syncthreads();
  if (tid < 256) {
    float sum = bum[tid];
#pragma unroll
    for (int k = 0; k < 12; k++) sum += part[k * 256 + tid];
    float upd = fmaxf(sum, 0.f);
    float u = updw[b * 3 + i];
    rnew[(b * 3 + i) * 256 + tid] = u * upd + (1.f - u) * xcs[tid];
  }
}

// ---------------- K4: sequential fa_am chain (3 iters) + tanh -> out ----------------
// block per batch row; m carried in LDS across iterations.
__global__ __launch_bounds__(512) void k_am(
    const float* __restrict__ w1, const float* __restrict__ b1,
    const float* __restrict__ w2, const float* __restrict__ b2,
    const float* __restrict__ Wam, const float* __restrict__ bam,
    const float* __restrict__ rnew, const float* __restrict__ readw,
    float* __restrict__ out) {
  __shared__ float xc[512], hs[512], part[2048], ms[256], red[16];
  int b = blockIdx.x, tid = threadIdx.x;
  if (tid < 256) ms[tid] = 0.f;
  __syncthreads();
  for (int i = 0; i < 3; i++) {
    if (tid < 256) xc[tid] = rnew[(b * 3 + i) * 256 + tid];
    else           xc[tid] = ms[tid - 256];
    __syncthreads();
    float t = b1[tid] + mm512_quad(xc, w1, part, tid);
    float mx = block_max(t, red);
    float e = expf(t - mx);
    float s = block_sum(e, red);
    hs[tid] = e / s;
    __syncthreads();
    float y = b2[tid] + mm512_quad(hs, w2, part, tid);
    float xav = xc[tid] * y;
    __syncthreads();             // part reads done before Wam overwrite
    hs[tid] = xav;               // reuse hs as xa buffer
    __syncthreads();
    // Wam pass: quad-col 8-way split-K (512 -> 256)
    {
      int jq = tid & 63, ks = tid >> 6;        // ks in 0..7
      const float* Wp = Wam + jq * 4;
      int c0 = ks * 64;
      float4 acc = {0.f, 0.f, 0.f, 0.f};
#pragma unroll 8
      for (int cc = 0; cc < 64; cc++) {
        int c = c0 + cc;
        float xv = hs[c];
        float4 wv = *(const float4*)(Wp + (size_t)c * 256);
        acc.x = fmaf(xv, wv.x, acc.x);
        acc.y = fmaf(xv, wv.y, acc.y);
        acc.z = fmaf(xv, wv.z, acc.z);
        acc.w = fmaf(xv, wv.w, acc.w);
      }
      ((float4*)part)[ks * 64 + jq] = acc;
    }
    __syncthreads();
    if (tid < 256) {
      float sum = bam[tid];
#pragma unroll
      for (int k = 0; k < 8; k++) sum += part[k * 256 + tid];
      ms[tid] = readw[b * 3 + i] * fmaxf(sum, 0.f);
    }
    __syncthreads();
  }
  if (tid < 256) out[b * 256 + tid] = tanhf(ms[tid]);
}

// ---------------- launch ----------------
extern "C" void kernel_launch(void* const* d_in, const int* in_sizes, int n_in,
                              void* d_out, int out_size, void* d_ws, size_t ws_size,
                              hipStream_t stream) {
  const float* x    = (const float*)d_in[0];
  const float* mem  = (const float*)d_in[1];
  const float* w1r  = (const float*)d_in[2];
  const float* b1r  = (const float*)d_in[3];
  const float* w2r  = (const float*)d_in[4];
  const float* b2r  = (const float*)d_in[5];
  const float* Wrd  = (const float*)d_in[6];
  const float* brd  = (const float*)d_in[7];
  const float* w1u  = (const float*)d_in[8];
  const float* b1u  = (const float*)d_in[9];
  const float* w2u  = (const float*)d_in[10];
  const float* b2u  = (const float*)d_in[11];
  const float* Wuw  = (const float*)d_in[12];
  const float* buw  = (const float*)d_in[13];
  const float* w1um = (const float*)d_in[14];
  const float* b1um = (const float*)d_in[15];
  const float* w2um = (const float*)d_in[16];
  const float* b2um = (const float*)d_in[17];
  const float* Wum  = (const float*)d_in[18];
  const float* bum  = (const float*)d_in[19];
  const float* w1am = (const float*)d_in[20];
  const float* b1am = (const float*)d_in[21];
  const float* w2am = (const float*)d_in[22];
  const float* b2am = (const float*)d_in[23];
  const float* Wam  = (const float*)d_in[24];
  const float* bam  = (const float*)d_in[25];

  float* ws   = (float*)d_ws;
  float* xr   = ws + WS_XR;
  float* updw = ws + WS_UPDW;
  float* rdw  = ws + WS_READW;
  float* pmax = ws + WS_PMAX;
  int*   pidx = (int*)(ws + WS_PIDX);
  float* rnew = ws + WS_RNEW;
  float* out  = (float*)d_out;

  k_fa_in<<<16, 512, 0, stream>>>(x, w1r, b1r, w2r, b2r, w1u, b1u, w2u, b2u,
                                  Wuw, buw, xr, updw);
  k_read<<<dim3(NTILES, 3), 512, 0, stream>>>(Wrd, brd, xr, pmax, pidx);
  k_um<<<48, 768, 0, stream>>>(mem, x, w1um, b1um, w2um, b2um, Wum, bum,
                               pmax, pidx, updw, rdw, rnew);
  k_am<<<16, 512, 0, stream>>>(w1am, b1am, w2am, b2am, Wam, bam, rnew, rdw, out);
}

// Round 4
// 510.117 us; speedup vs baseline: 1.7065x; 1.0224x over previous
//
#include <hip/hip_runtime.h>
#include <cfloat>
#include <cmath>

constexpr int NTILES = 79;   // ceil(10000 / 128) for k_read

// ---------------- workspace layout (floats) ----------------
enum : int {
  WS_XR    = 0,        // 16*512
  WS_UPDW  = 8192,     // 48
  WS_READW = 8240,     // 48
  WS_PMAX  = 8288,     // 3*16*79
  WS_PIDX  = 12080,    // 3*16*79 (ints)
  WS_RNEW  = 15872,    // 48*256
  WS_M     = 28160,    // 16*256  running m
  WS_XC    = 32256,    // 48*768  concat(mem_row, x)
  WS_TPA   = 69120,    // 2*4*16*512  phase-A logit partials
  WS_HA    = 134656,   // 2*16*512    phase-A probs
  WS_YPA   = 151040,   // 2*4*16*512  phase-A mm2 partials
  WS_TPU   = 216576,   // 6*48*768
  WS_HU    = 437760,   // 48*768
  WS_YPU   = 474624,   // 6*48*768
  WS_WPU   = 695808,   // 6*48*256
  WS_TPM   = 769536,   // 4*16*512
  WS_HM    = 802304,   // 16*512
  WS_YPM   = 810496,   // 4*16*512
  WS_WPM   = 843264,   // 4*16*256
};                     // total ~3.4 MB << ws_size

// ---------------- reductions (wave = 64) ----------------
__device__ __forceinline__ float wave_sum(float v) {
#pragma unroll
  for (int o = 32; o > 0; o >>= 1) v += __shfl_xor(v, o);
  return v;
}
__device__ __forceinline__ float wave_max(float v) {
#pragma unroll
  for (int o = 32; o > 0; o >>= 1) v = fmaxf(v, __shfl_xor(v, o));
  return v;
}
__device__ __forceinline__ float block_sum(float v, float* red) {
  int lane = threadIdx.x & 63, w = threadIdx.x >> 6, nw = blockDim.x >> 6;
  v = wave_sum(v);
  __syncthreads();
  if (lane == 0) red[w] = v;
  __syncthreads();
  float s = 0.f;
  for (int k = 0; k < nw; k++) s += red[k];
  return s;
}
__device__ __forceinline__ float block_max(float v, float* red) {
  int lane = threadIdx.x & 63, w = threadIdx.x >> 6, nw = blockDim.x >> 6;
  v = wave_max(v);
  __syncthreads();
  if (lane == 0) red[w] = v;
  __syncthreads();
  float s = -FLT_MAX;
  for (int k = 0; k < nw; k++) s = fmaxf(s, red[k]);
  return s;
}

// ---------------- shared mm core ----------------
// 512 threads = 8 waves; wave w -> rows (2w, 2w+1) of a 16-row group;
// lane -> 2 consecutive cols. Computes a 16x128 tile over a 128-K slice.
// Each weight element is read by exactly ONE block in the grid.
__device__ __forceinline__ void mm_tile16(
    const float* __restrict__ xs,          // LDS [16][128]
    const float* __restrict__ W, int ldw,  // global weights, row stride ldw
    int koff, int jbase, float2& ra, float2& rb) {
  int lane = threadIdx.x & 63, w = threadIdx.x >> 6;
  const float* xa = xs + (w * 2) * 128;
  const float* xb = xa + 128;
  const float* Wp = W + (size_t)koff * ldw + jbase + lane * 2;
  float a00 = 0.f, a01 = 0.f, a10 = 0.f, a11 = 0.f;
#pragma unroll 8
  for (int k = 0; k < 128; k++) {
    float2 wv = *(const float2*)(Wp + (size_t)k * ldw);
    float xav = xa[k], xbv = xb[k];
    a00 = fmaf(xav, wv.x, a00); a01 = fmaf(xav, wv.y, a01);
    a10 = fmaf(xbv, wv.x, a10); a11 = fmaf(xbv, wv.y, a11);
  }
  ra = make_float2(a00, a01);
  rb = make_float2(a10, a11);
}
__device__ __forceinline__ void store_tile16(
    float* __restrict__ T, int ldt, int jbase, float2 ra, float2 rb) {
  int lane = threadIdx.x & 63, w = threadIdx.x >> 6;
  int r0 = w * 2, j0 = jbase + lane * 2;
  *(float2*)(T + (size_t)r0 * ldt + j0) = ra;
  *(float2*)(T + (size_t)(r0 + 1) * ldt + j0) = rb;
}

// ================= Phase A: fa_r + fa_u + upd_w =================
// A1: logit partials for both mats. grid (4 jt, 4 ks, 2 mat).
__global__ __launch_bounds__(512) void k_mm1_a(
    const float* __restrict__ x, const float* __restrict__ w1r,
    const float* __restrict__ w1u, float* __restrict__ TPA) {
  __shared__ float xs[16 * 128];
  int jt = blockIdx.x, ks = blockIdx.y, m = blockIdx.z, tid = threadIdx.x;
  for (int t = tid; t < 2048; t += 512) {
    int b = t >> 7, kk = t & 127;
    xs[t] = x[b * 512 + ks * 128 + kk];
  }
  __syncthreads();
  float2 ra, rb;
  mm_tile16(xs, m ? w1u : w1r, 512, ks * 128, jt * 128, ra, rb);
  store_tile16(TPA + (size_t)((m * 4 + ks) * 16) * 512, 512, jt * 128, ra, rb);
}

// A2: assemble + softmax. grid (16 b, 2 mat), 512 thr.
__global__ __launch_bounds__(512) void k_sm_a(
    const float* __restrict__ TPA, const float* __restrict__ b1r,
    const float* __restrict__ b1u, float* __restrict__ HA) {
  __shared__ float red[16];
  int b = blockIdx.x, m = blockIdx.y, tid = threadIdx.x;
  float t = (m ? b1u : b1r)[tid];
#pragma unroll
  for (int ks = 0; ks < 4; ks++)
    t += TPA[(size_t)((m * 4 + ks) * 16 + b) * 512 + tid];
  float mx = block_max(t, red);
  float e = expf(t - mx);
  float s = block_sum(e, red);
  HA[(size_t)(m * 16 + b) * 512 + tid] = e / s;
}

// A3: h @ w2 partials. grid (4, 4, 2).
__global__ __launch_bounds__(512) void k_mm2_a(
    const float* __restrict__ HA, const float* __restrict__ w2r,
    const float* __restrict__ w2u, float* __restrict__ YPA) {
  __shared__ float xs[16 * 128];
  int jt = blockIdx.x, ks = blockIdx.y, m = blockIdx.z, tid = threadIdx.x;
  for (int t = tid; t < 2048; t += 512) {
    int b = t >> 7, kk = t & 127;
    xs[t] = HA[(size_t)(m * 16 + b) * 512 + ks * 128 + kk];
  }
  __syncthreads();
  float2 ra, rb;
  mm_tile16(xs, m ? w2u : w2r, 512, ks * 128, jt * 128, ra, rb);
  store_tile16(YPA + (size_t)((m * 4 + ks) * 16) * 512, 512, jt * 128, ra, rb);
}

// A4: xr = x*(yr+b2r); xu -> updw sigmoid dots; zero M. grid 16, 512 thr.
__global__ __launch_bounds__(512) void k_fin_a(
    const float* __restrict__ x, const float* __restrict__ YPA,
    const float* __restrict__ b2r, const float* __restrict__ b2u,
    const float* __restrict__ Wuw, const float* __restrict__ buw,
    float* __restrict__ XR, float* __restrict__ UPDW, float* __restrict__ M) {
  __shared__ float red[16];
  int b = blockIdx.x, tid = threadIdx.x;
  float yr = b2r[tid], yu = b2u[tid];
#pragma unroll
  for (int ks = 0; ks < 4; ks++) {
    yr += YPA[(size_t)((0 + ks) * 16 + b) * 512 + tid];
    yu += YPA[(size_t)((4 + ks) * 16 + b) * 512 + tid];
  }
  float xv = x[b * 512 + tid];
  XR[b * 512 + tid] = xv * yr;
  float xu = xv * yu;
  if (tid < 256) M[b * 256 + tid] = 0.f;
  for (int i = 0; i < 3; i++) {
    float si = block_sum(xu * Wuw[tid * 3 + i], red);
    if (tid == 0) UPDW[b * 3 + i] = 1.f / (1.f + expf(-(si + buw[i])));
  }
}

// ================= K2: read matmul + per-tile max/argmax (unchanged) ========
__global__ __launch_bounds__(512) void k_read(
    const float* __restrict__ W, const float* __restrict__ brd,
    const float* __restrict__ xr,
    float* __restrict__ pmax, int* __restrict__ pidx) {
  __shared__ __align__(16) float xs[16 * 512];
  int tid = threadIdx.x, lane = tid & 63, w = tid >> 6;
  int i = blockIdx.y, tile = blockIdx.x;
  {
    const float4* s4 = (const float4*)xr;
    float4* d4 = (float4*)xs;
    for (int t = tid; t < 2048; t += 512) d4[t] = s4[t];
  }
  __syncthreads();
  int b0 = w * 2, b1 = b0 + 1;
  int s0 = tile * 128 + lane * 2;
  int sC = (s0 > 9998) ? 9998 : s0;
  const float* Wp = W + i * 10000 + sC;
  const float* xap = xs + b0 * 512;
  const float* xbp = xs + b1 * 512;
  float a00 = 0.f, a01 = 0.f, a10 = 0.f, a11 = 0.f;
#pragma unroll 8
  for (int c = 0; c < 512; c += 4) {
    float4 xa = *(const float4*)(xap + c);
    float4 xb = *(const float4*)(xbp + c);
    float2 w0 = *(const float2*)(Wp + (size_t)(c + 0) * 30000);
    float2 w1 = *(const float2*)(Wp + (size_t)(c + 1) * 30000);
    float2 w2 = *(const float2*)(Wp + (size_t)(c + 2) * 30000);
    float2 w3 = *(const float2*)(Wp + (size_t)(c + 3) * 30000);
    a00 = fmaf(xa.x, w0.x, a00); a01 = fmaf(xa.x, w0.y, a01);
    a10 = fmaf(xb.x, w0.x, a10); a11 = fmaf(xb.x, w0.y, a11);
    a00 = fmaf(xa.y, w1.x, a00); a01 = fmaf(xa.y, w1.y, a01);
    a10 = fmaf(xb.y, w1.x, a10); a11 = fmaf(xb.y, w1.y, a11);
    a00 = fmaf(xa.z, w2.x, a00); a01 = fmaf(xa.z, w2.y, a01);
    a10 = fmaf(xb.z, w2.x, a10); a11 = fmaf(xb.z, w2.y, a11);
    a00 = fmaf(xa.w, w3.x, a00); a01 = fmaf(xa.w, w3.y, a01);
    a10 = fmaf(xb.w, w3.x, a10); a11 = fmaf(xb.w, w3.y, a11);
  }
  float2 bb = *(const float2*)(brd + i * 10000 + sC);
  bool ok0 = (s0 < 10000), ok1 = (s0 + 1 < 10000);
  float v00 = a00 + bb.x, v01 = a01 + bb.y;
  float v10 = a10 + bb.x, v11 = a11 + bb.y;
  float bv0 = ok0 ? v00 : -FLT_MAX; int bi0 = s0;
  if (ok1 && v01 > bv0) { bv0 = v01; bi0 = s0 + 1; }
  float bv1 = ok0 ? v10 : -FLT_MAX; int bi1 = s0;
  if (ok1 && v11 > bv1) { bv1 = v11; bi1 = s0 + 1; }
#pragma unroll
  for (int o = 32; o > 0; o >>= 1) {
    float ov = __shfl_down(bv0, o); int oi = __shfl_down(bi0, o);
    if (ov > bv0) { bv0 = ov; bi0 = oi; }
    ov = __shfl_down(bv1, o); oi = __shfl_down(bi1, o);
    if (ov > bv1) { bv1 = ov; bi1 = oi; }
  }
  if (lane == 0) {
    int base = (i * 16 + b0) * NTILES + tile;
    pmax[base] = bv0; pidx[base] = bi0;
    base = (i * 16 + b1) * NTILES + tile;
    pmax[base] = bv1; pidx[base] = bi1;
  }
}

// ============ B: argmax finalize + gather XC = [mem_row, x] ============
__global__ __launch_bounds__(768) void k_gather(
    const float* __restrict__ mem, const float* __restrict__ x,
    const float* __restrict__ pmax, const int* __restrict__ pidx,
    float* __restrict__ READW, float* __restrict__ XC) {
  __shared__ int sidx;
  int bi = blockIdx.x, b = bi / 3, i = bi % 3;
  int tid = threadIdx.x, lane = tid & 63;
  if (tid < 64) {
    float bv = -FLT_MAX; int bix = 0;
    const float* pm = pmax + (i * 16 + b) * NTILES;
    const int* pi = pidx + (i * 16 + b) * NTILES;
    for (int t = lane; t < NTILES; t += 64) {
      float v = pm[t]; int ix = pi[t];
      if (v > bv || (v == bv && ix < bix)) { bv = v; bix = ix; }
    }
#pragma unroll
    for (int o = 32; o > 0; o >>= 1) {
      float ov = __shfl_down(bv, o); int oi = __shfl_down(bix, o);
      if (ov > bv || (ov == bv && oi < bix)) { bv = ov; bix = oi; }
    }
    if (lane == 0) { sidx = bix; READW[bi] = tanhf(bv); }
  }
  __syncthreads();
  if (tid < 256) XC[(size_t)bi * 768 + tid] = mem[((size_t)b * 10000 + sidx) * 256 + tid];
  else           XC[(size_t)bi * 768 + tid] = x[b * 512 + (tid - 256)];
}

// ================= Phase C: fa_um + W_um + gate (48 indep rows) ========
__global__ __launch_bounds__(512) void k_mm1_u(
    const float* __restrict__ XC, const float* __restrict__ w1um,
    float* __restrict__ TPU) {
  __shared__ float xs[16 * 128];
  int jt = blockIdx.x, ks = blockIdx.y, g = blockIdx.z, tid = threadIdx.x;
  for (int t = tid; t < 2048; t += 512) {
    int r = t >> 7, kk = t & 127;
    xs[t] = XC[(size_t)(g * 16 + r) * 768 + ks * 128 + kk];
  }
  __syncthreads();
  float2 ra, rb;
  mm_tile16(xs, w1um, 768, ks * 128, jt * 128, ra, rb);
  store_tile16(TPU + (size_t)(ks * 48 + g * 16) * 768, 768, jt * 128, ra, rb);
}

__global__ __launch_bounds__(768) void k_sm_u(
    const float* __restrict__ TPU, const float* __restrict__ b1um,
    float* __restrict__ HU) {
  __shared__ float red[16];
  int bi = blockIdx.x, tid = threadIdx.x;
  float t = b1um[tid];
#pragma unroll
  for (int ks = 0; ks < 6; ks++)
    t += TPU[(size_t)(ks * 48 + bi) * 768 + tid];
  float mx = block_max(t, red);
  float e = expf(t - mx);
  float s = block_sum(e, red);
  HU[(size_t)bi * 768 + tid] = e / s;
}

__global__ __launch_bounds__(512) void k_mm2_u(
    const float* __restrict__ HU, const float* __restrict__ w2um,
    float* __restrict__ YPU) {
  __shared__ float xs[16 * 128];
  int jt = blockIdx.x, ks = blockIdx.y, g = blockIdx.z, tid = threadIdx.x;
  for (int t = tid; t < 2048; t += 512) {
    int r = t >> 7, kk = t & 127;
    xs[t] = HU[(size_t)(g * 16 + r) * 768 + ks * 128 + kk];
  }
  __syncthreads();
  float2 ra, rb;
  mm_tile16(xs, w2um, 768, ks * 128, jt * 128, ra, rb);
  store_tile16(YPU + (size_t)(ks * 48 + g * 16) * 768, 768, jt * 128, ra, rb);
}

// C4: assemble xu = xc*(y+b2um) for this K-slice, then @ W_um partials.
__global__ __launch_bounds__(512) void k_wum(
    const float* __restrict__ YPU, const float* __restrict__ XC,
    const float* __restrict__ b2um, const float* __restrict__ Wum,
    float* __restrict__ WPU) {
  __shared__ float xs[16 * 128];
  int jt = blockIdx.x, ks = blockIdx.y, g = blockIdx.z, tid = threadIdx.x;
  for (int t = tid; t < 2048; t += 512) {
    int r = t >> 7, kk = t & 127;
    int bi = g * 16 + r, k = ks * 128 + kk;
    float y = b2um[k];
#pragma unroll
    for (int k2 = 0; k2 < 6; k2++) y += YPU[(size_t)(k2 * 48 + bi) * 768 + k];
    xs[t] = XC[(size_t)bi * 768 + k] * y;
  }
  __syncthreads();
  float2 ra, rb;
  mm_tile16(xs, Wum, 256, ks * 128, jt * 128, ra, rb);
  store_tile16(WPU + (size_t)(ks * 48 + g * 16) * 256, 256, jt * 128, ra, rb);
}

// C5: rnew = u*relu(sum+bum) + (1-u)*xc. grid 48, 256 thr.
__global__ __launch_bounds__(256) void k_fin_u(
    const float* __restrict__ WPU, const float* __restrict__ XC,
    const float* __restrict__ bum, const float* __restrict__ UPDW,
    float* __restrict__ RNEW) {
  int bi = blockIdx.x, tid = threadIdx.x;
  float s = bum[tid];
#pragma unroll
  for (int ks = 0; ks < 6; ks++)
    s += WPU[(size_t)(ks * 48 + bi) * 256 + tid];
  float u = UPDW[bi];
  RNEW[(size_t)bi * 256 + tid] = u * fmaxf(s, 0.f) + (1.f - u) * XC[(size_t)bi * 768 + tid];
}

// ================= Phase D: sequential fa_am chain (per i) =============
__global__ __launch_bounds__(512) void k_mm1_m(
    const float* __restrict__ RNEW, const float* __restrict__ M,
    const float* __restrict__ w1am, float* __restrict__ TPM, int i) {
  __shared__ float xs[16 * 128];
  int jt = blockIdx.x, ks = blockIdx.y, tid = threadIdx.x;
  for (int t = tid; t < 2048; t += 512) {
    int b = t >> 7, kk = t & 127;
    xs[t] = (ks < 2) ? RNEW[(size_t)(b * 3 + i) * 256 + ks * 128 + kk]
                     : M[b * 256 + (ks - 2) * 128 + kk];
  }
  __syncthreads();
  float2 ra, rb;
  mm_tile16(xs, w1am, 512, ks * 128, jt * 128, ra, rb);
  store_tile16(TPM + (size_t)(ks * 16) * 512, 512, jt * 128, ra, rb);
}

__global__ __launch_bounds__(512) void k_sm_m(
    const float* __restrict__ TPM, const float* __restrict__ b1am,
    float* __restrict__ HM) {
  __shared__ float red[16];
  int b = blockIdx.x, tid = threadIdx.x;
  float t = b1am[tid];
#pragma unroll
  for (int ks = 0; ks < 4; ks++)
    t += TPM[(size_t)(ks * 16 + b) * 512 + tid];
  float mx = block_max(t, red);
  float e = expf(t - mx);
  float s = block_sum(e, red);
  HM[(size_t)b * 512 + tid] = e / s;
}

__global__ __launch_bounds__(512) void k_mm2_m(
    const float* __restrict__ HM, const float* __restrict__ w2am,
    float* __restrict__ YPM) {
  __shared__ float xs[16 * 128];
  int jt = blockIdx.x, ks = blockIdx.y, tid = threadIdx.x;
  for (int t = tid; t < 2048; t += 512) {
    int b = t >> 7, kk = t & 127;
    xs[t] = HM[(size_t)b * 512 + ks * 128 + kk];
  }
  __syncthreads();
  float2 ra, rb;
  mm_tile16(xs, w2am, 512, ks * 128, jt * 128, ra, rb);
  store_tile16(YPM + (size_t)(ks * 16) * 512, 512, jt * 128, ra, rb);
}

// D4: assemble xa = xc*(y+b2am) for this K-slice, then @ W_am partials.
__global__ __launch_bounds__(512) void k_wam(
    const float* __restrict__ YPM, const float* __restrict__ RNEW,
    const float* __restrict__ M, const float* __restrict__ b2am,
    const float* __restrict__ Wam, float* __restrict__ WPM, int i) {
  __shared__ float xs[16 * 128];
  int jt = blockIdx.x, ks = blockIdx.y, tid = threadIdx.x;
  for (int t = tid; t < 2048; t += 512) {
    int b = t >> 7, kk = t & 127;
    int k = ks * 128 + kk;
    float xc = (ks < 2) ? RNEW[(size_t)(b * 3 + i) * 256 + k]
                        : M[b * 256 + k - 256];
    float y = b2am[k];
#pragma unroll
    for (int k2 = 0; k2 < 4; k2++) y += YPM[(size_t)(k2 * 16 + b) * 512 + k];
    xs[t] = xc * y;
  }
  __syncthreads();
  float2 ra, rb;
  mm_tile16(xs, Wam, 256, ks * 128, jt * 128, ra, rb);
  store_tile16(WPM + (size_t)(ks * 16) * 256, 256, jt * 128, ra, rb);
}

// D5: m' = readw * relu(sum + bam); write M, and tanh->out on last iter.
__global__ __launch_bounds__(256) void k_fin_m(
    const float* __restrict__ WPM, const float* __restrict__ bam,
    const float* __restrict__ READW, float* __restrict__ M,
    float* __restrict__ out, int i, int last) {
  int b = blockIdx.x, tid = threadIdx.x;
  float s = bam[tid];
#pragma unroll
  for (int ks = 0; ks < 4; ks++)
    s += WPM[(size_t)(ks * 16 + b) * 256 + tid];
  float mv = READW[b * 3 + i] * fmaxf(s, 0.f);
  M[b * 256 + tid] = mv;
  if (last) out[b * 256 + tid] = tanhf(mv);
}

// ---------------- launch ----------------
extern "C" void kernel_launch(void* const* d_in, const int* in_sizes, int n_in,
                              void* d_out, int out_size, void* d_ws, size_t ws_size,
                              hipStream_t stream) {
  const float* x    = (const float*)d_in[0];
  const float* mem  = (const float*)d_in[1];
  const float* w1r  = (const float*)d_in[2];
  const float* b1r  = (const float*)d_in[3];
  const float* w2r  = (const float*)d_in[4];
  const float* b2r  = (const float*)d_in[5];
  const float* Wrd  = (const float*)d_in[6];
  const float* brd  = (const float*)d_in[7];
  const float* w1u  = (const float*)d_in[8];
  const float* b1u  = (const float*)d_in[9];
  const float* w2u  = (const float*)d_in[10];
  const float* b2u  = (const float*)d_in[11];
  const float* Wuw  = (const float*)d_in[12];
  const float* buw  = (const float*)d_in[13];
  const float* w1um = (const float*)d_in[14];
  const float* b1um = (const float*)d_in[15];
  const float* w2um = (const float*)d_in[16];
  const float* b2um = (const float*)d_in[17];
  const float* Wum  = (const float*)d_in[18];
  const float* bum  = (const float*)d_in[19];
  const float* w1am = (const float*)d_in[20];
  const float* b1am = (const float*)d_in[21];
  const float* w2am = (const float*)d_in[22];
  const float* b2am = (const float*)d_in[23];
  const float* Wam  = (const float*)d_in[24];
  const float* bam  = (const float*)d_in[25];

  float* ws   = (float*)d_ws;
  float* XR   = ws + WS_XR;
  float* UPDW = ws + WS_UPDW;
  float* RDW  = ws + WS_READW;
  float* PMAX = ws + WS_PMAX;
  int*   PIDX = (int*)(ws + WS_PIDX);
  float* RNEW = ws + WS_RNEW;
  float* M    = ws + WS_M;
  float* XC   = ws + WS_XC;
  float* TPA  = ws + WS_TPA;
  float* HA   = ws + WS_HA;
  float* YPA  = ws + WS_YPA;
  float* TPU  = ws + WS_TPU;
  float* HU   = ws + WS_HU;
  float* YPU  = ws + WS_YPU;
  float* WPU  = ws + WS_WPU;
  float* TPM  = ws + WS_TPM;
  float* HM   = ws + WS_HM;
  float* YPM  = ws + WS_YPM;
  float* WPM  = ws + WS_WPM;
  float* out  = (float*)d_out;

  // Phase A
  k_mm1_a<<<dim3(4, 4, 2), 512, 0, stream>>>(x, w1r, w1u, TPA);
  k_sm_a <<<dim3(16, 2),   512, 0, stream>>>(TPA, b1r, b1u, HA);
  k_mm2_a<<<dim3(4, 4, 2), 512, 0, stream>>>(HA, w2r, w2u, YPA);
  k_fin_a<<<16,            512, 0, stream>>>(x, YPA, b2r, b2u, Wuw, buw,
                                             XR, UPDW, M);
  // Read path
  k_read  <<<dim3(NTILES, 3), 512, 0, stream>>>(Wrd, brd, XR, PMAX, PIDX);
  k_gather<<<48,              768, 0, stream>>>(mem, x, PMAX, PIDX, RDW, XC);
  // Phase C (update rows, all 48 independent)
  k_mm1_u<<<dim3(6, 6, 3), 512, 0, stream>>>(XC, w1um, TPU);
  k_sm_u <<<48,            768, 0, stream>>>(TPU, b1um, HU);
  k_mm2_u<<<dim3(6, 6, 3), 512, 0, stream>>>(HU, w2um, YPU);
  k_wum  <<<dim3(2, 6, 3), 512, 0, stream>>>(YPU, XC, b2um, Wum, WPU);
  k_fin_u<<<48,            256, 0, stream>>>(WPU, XC, bum, UPDW, RNEW);
  // Phase D (sequential in i through M)
  for (int i = 0; i < 3; i++) {
    k_mm1_m<<<dim3(4, 4), 512, 0, stream>>>(RNEW, M, w1am, TPM, i);
    k_sm_m <<<16,         512, 0, stream>>>(TPM, b1am, HM);
    k_mm2_m<<<dim3(4, 4), 512, 0, stream>>>(HM, w2am, YPM);
    k_wam  <<<dim3(2, 4), 512, 0, stream>>>(YPM, RNEW, M, b2am, Wam, WPM, i);
    k_fin_m<<<16,         256, 0, stream>>>(WPM, bam, RDW, M, out, i, i == 2);
  }
}